// Round 10
// baseline (4933.446 us; speedup 1.0000x reference)
//
#include <hip/hip_runtime.h>

// Problem constants (fixed by the reference).
#define TSTEPS 256
#define NNODE  100000
#define NEDGE  8192
#define KBLK   16                    // persistent-scan blocks (co-resident)
#define NTHR   1024
#define EPB    (NEDGE / KBLK)        // 512 edges per block in phase G

static_assert(KBLK * NTHR == 2 * NEDGE, "phase-C slot mapping requires K*T == 2E");

constexpr float MU_P  = 0.1f;
constexpr float MU_M  = 0.05f;
constexpr float RHO_  = 16.0f;
constexpr float CLO   = 1e-5f;
constexpr float CHI   = 1.0f - 1e-5f;
constexpr float SCALE = 1048576.0f;          // 2^20 fixed-point for delta
constexpr float INVSC = 1.0f / 1048576.0f;

// f32 sentinel: real X values are positive finite, 0xFFFFFFFF impossible.
#define SENT32 0xFFFFFFFFu

__device__ __forceinline__ float sigm(float x) {
  return 1.0f / (1.0f + __expf(-x));
}
__device__ __forceinline__ float x0_of(const float* logit, int n) {
  return fminf(fmaxf(sigm(logit[n]), CLO), CHI);
}
__device__ __forceinline__ int edge_at(const int* __restrict__ arr, int idx,
                                       int is64) {
  if (is64) return (int)((const long long*)arr)[idx];
  return arr[idx];
}

// ---------------------------------------------------------------------------
// k_detect: int32 vs int64 materialization of u/v (runtime-proof either way).
// ---------------------------------------------------------------------------
__global__ void k_detect(const int* __restrict__ u, const int* __restrict__ v,
                         unsigned* __restrict__ dflags) {
  if (threadIdx.x != 0 || blockIdx.x != 0) return;
  const unsigned* a = (const unsigned*)u;
  const unsigned* b = (const unsigned*)v;
  bool i64 = true;
  for (int k = 1; k < 128; k += 2) i64 = i64 && (a[k] == 0u) && (b[k] == 0u);
  dflags[0] = i64 ? 1u : 0u;
}

// ---------------------------------------------------------------------------
// k_init: xs = clip(sigmoid(logit)); delta/claim/barrier zeroed; output X
// row 0 = sigmoid(logit) UNCLIPPED f32; X rows 1..T-1 = sentinel.
// Re-runs every call -> deterministic replays.
// ---------------------------------------------------------------------------
__global__ void k_init(const float* __restrict__ logit,
                       float* __restrict__ xs,
                       unsigned* __restrict__ delta,
                       unsigned* __restrict__ claim,
                       unsigned* __restrict__ bar,
                       float* __restrict__ outX) {
  const int i = blockIdx.x * blockDim.x + threadIdx.x;
  const int stride = gridDim.x * blockDim.x;

  for (int n = i; n < NNODE; n += stride) {
    xs[n]    = x0_of(logit, n);
    delta[n] = 0u;
    claim[n] = 0u;
    outX[n]  = sigm(logit[n]);           // row 0, unclipped, f32
  }
  unsigned* outX32 = (unsigned*)outX;
  const int total = TSTEPS * NNODE;
  for (int w = NNODE + i; w < total; w += stride) outX32[w] = SENT32;
  if (i < 2) bar[i] = 0u;
}

// ---------------------------------------------------------------------------
// Global barrier across the KBLK co-resident blocks (R3 design, exonerated:
// its only "failure" was the output-dtype bug). Agent-scope monotone
// generation barrier with device fences on both sides.
// ---------------------------------------------------------------------------
__device__ __forceinline__ void gbar(unsigned* bar, unsigned* gen_local) {
  __syncthreads();
  if (threadIdx.x == 0) {
    __threadfence();
    const unsigned target = ++(*gen_local);
    unsigned old = __hip_atomic_fetch_add(&bar[0], 1u, __ATOMIC_ACQ_REL,
                                          __HIP_MEMORY_SCOPE_AGENT);
    if (old == KBLK - 1) {
      __hip_atomic_store(&bar[0], 0u, __ATOMIC_RELAXED, __HIP_MEMORY_SCOPE_AGENT);
      __hip_atomic_store(&bar[1], target, __ATOMIC_RELEASE, __HIP_MEMORY_SCOPE_AGENT);
    } else {
      while (__hip_atomic_load(&bar[1], __ATOMIC_ACQUIRE,
                               __HIP_MEMORY_SCOPE_AGENT) < target) {
        __builtin_amdgcn_s_sleep(1);
      }
    }
    __threadfence();
  }
  __syncthreads();
}

// ---------------------------------------------------------------------------
// k_scan: the whole 255-step scan in ONE persistent dispatch.
//   Phase G (512 edges/block): gather xs (agent loads), kappa row t (f32
//     stores), fixed-point delta atomicAdds (device-scope).
//   Phase C (1024 slots/block): claim-dedup (unique owner per touched node),
//     acc = exch(delta,0); xs = clip(xs+acc); scatter f32 into X row t+1.
// Two gbar per step replace two kernel launches (~3-4 us each) with
// ~1.6 us of barrier latency.
// ---------------------------------------------------------------------------
__global__ __launch_bounds__(NTHR, 1) void k_scan(
    const int* __restrict__ u, const int* __restrict__ v,
    const float* __restrict__ sp, const float* __restrict__ sm,
    const float* __restrict__ theta,
    float* __restrict__ xs, unsigned* __restrict__ delta,
    unsigned* __restrict__ claim, unsigned* __restrict__ bar,
    const unsigned* __restrict__ dflags,
    float* __restrict__ outX,
    float* __restrict__ outKp, float* __restrict__ outKm) {
  const int tid  = threadIdx.x;
  const int is64 = (int)dflags[0];
  const float epsp = sigm(theta[0]) * 0.5f;
  const float epsm = 0.5f + sigm(theta[1]) * 0.5f;

  unsigned gen = 0;

  for (int t = 0; t < TSTEPS; ++t) {
    // ---- Phase G: kappa row t from X[t]; accumulate delta (t < T-1) ----
    if (tid < EPB) {
      const int e  = t * NEDGE + blockIdx.x * EPB + tid;   // coalesced
      const int un = edge_at(u, e, is64);
      const int vn = edge_at(v, e, is64);
      const float xu = __hip_atomic_load(&xs[un], __ATOMIC_RELAXED,
                                         __HIP_MEMORY_SCOPE_AGENT);
      const float xv = __hip_atomic_load(&xs[vn], __ATOMIC_RELAXED,
                                         __HIP_MEMORY_SCOPE_AGENT);
      const float d  = xv - xu;               // = -(Xu - Xv)
      const float ad = fabsf(d);
      outKp[e] = sigm(RHO_ * (epsp - ad));
      outKm[e] = sigm(RHO_ * (ad - epsm));
      if (t < TSTEPS - 1) {
        const float w  = MU_P * sp[e] - MU_M * sm[e];
        const int   iv = __float2int_rn(w * d * SCALE);
        atomicAdd(&delta[un], (unsigned)iv);      // device-scope int adds:
        atomicAdd(&delta[vn], (unsigned)(-iv));   // exact & commutative
      }
    }
    gbar(bar, &gen);
    if (t == TSTEPS - 1) break;

    // ---- Phase C: one owner per touched node applies the step ----
    {
      const int s = blockIdx.x * NTHR + tid;     // 0..2*NEDGE-1
      const int node = (s < NEDGE) ? edge_at(u, t * NEDGE + s, is64)
                                   : edge_at(v, t * NEDGE + s - NEDGE, is64);
      const unsigned epoch = (unsigned)(t + 1);
      if (atomicExch(&claim[node], epoch) != epoch) {   // unique owner
        const int acc = (int)atomicExch(&delta[node], 0u);
        const float x0 = __hip_atomic_load(&xs[node], __ATOMIC_RELAXED,
                                           __HIP_MEMORY_SCOPE_AGENT);
        const float nv = fminf(fmaxf(x0 + (float)acc * INVSC, CLO), CHI);
        __hip_atomic_store(&xs[node], nv, __ATOMIC_RELAXED,
                           __HIP_MEMORY_SCOPE_AGENT);
        outX[(size_t)(t + 1) * NNODE + node] = nv;      // f32 scatter
      }
    }
    gbar(bar, &gen);
  }
}

// ---------------------------------------------------------------------------
// k_fill: resolve sentinels by fill-forward; coalesced per-node columns.
// ---------------------------------------------------------------------------
__global__ void k_fill(const float* __restrict__ logit,
                       unsigned* __restrict__ outX32) {
  const int n = blockIdx.x * blockDim.x + threadIdx.x;
  if (n >= NNODE) return;
  unsigned carry = __float_as_uint(x0_of(logit, n));   // untouched rows = clip(X0)
  for (int t = 1; t < TSTEPS; ++t) {
    const size_t idx = (size_t)t * NNODE + n;
    const unsigned w = outX32[idx];
    if (w == SENT32) outX32[idx] = carry;
    else             carry = w;
  }
}

// ---------------------------------------------------------------------------
// kDiag: forced host-probe failure encoding only (layout/ws sanity).
// ---------------------------------------------------------------------------
__global__ void kDiag(float* __restrict__ outX, int b0, int b1) {
  if (threadIdx.x != 0 || blockIdx.x != 0) return;
  outX[0] = (float)(2048 + 1024 * b0 + 512 * b1);
}

// ---------------------------------------------------------------------------
extern "C" void kernel_launch(void* const* d_in, const int* in_sizes, int n_in,
                              void* d_out, int out_size, void* d_ws, size_t ws_size,
                              hipStream_t stream) {
  const float* logit = (const float*)d_in[0];
  const float* theta = (const float*)d_in[1];
  const int*   u     = (const int*)d_in[2];
  const int*   v     = (const int*)d_in[3];
  const float* sp    = (const float*)d_in[4];
  const float* sm    = (const float*)d_in[5];

  float* outX  = (float*)d_out;                         // [T, N] f32
  float* outKp = outX + (size_t)TSTEPS * NNODE;         // [T, E] f32
  float* outKm = outKp + (size_t)TSTEPS * NEDGE;        // [T, E] f32

  const int b0 = (n_in == 6 &&
                  in_sizes[0] == NNODE && in_sizes[1] == 2 &&
                  in_sizes[2] == TSTEPS * NEDGE && in_sizes[3] == TSTEPS * NEDGE &&
                  in_sizes[4] == TSTEPS * NEDGE && in_sizes[5] == TSTEPS * NEDGE) ? 1 : 0;
  const int b1 = (ws_size >= 1250000) ? 1 : 0;
  if (!b0 || !b1) {
    kDiag<<<1, 64, 0, stream>>>(outX, b0, b1);
    return;
  }

  // workspace: xs (N f32) | delta (N u32) | claim (N u32) | dflags (8 u32)
  char* ws = (char*)d_ws;
  float*    xs     = (float*)ws;
  unsigned* delta  = (unsigned*)(ws + (size_t)NNODE * 4);
  unsigned* claim  = (unsigned*)(ws + (size_t)2 * NNODE * 4);
  unsigned* dflags = (unsigned*)(ws + (size_t)3 * NNODE * 4);
  unsigned* bar    = dflags + 4;                        // 2 slots

  k_detect<<<1, 64, 0, stream>>>(u, v, dflags);
  k_init<<<2048, 256, 0, stream>>>(logit, xs, delta, claim, bar, outX);
  k_scan<<<KBLK, NTHR, 0, stream>>>(u, v, sp, sm, theta, xs, delta, claim,
                                    bar, dflags, outX, outKp, outKm);
  k_fill<<<(NNODE + 255) / 256, 256, 0, stream>>>(logit, (unsigned*)d_out);
}